// Round 2
// baseline (23689.171 us; speedup 1.0000x reference)
//
#include <hip/hip_runtime.h>
#include <hip/hip_bf16.h>

#define T_STEPS 70
#define BATCH   64
#define NTOKEN  33278
#define NINP    400
#define NHID    1150
#define MROWS   (T_STEPS * BATCH)   // 4480

// ---------------- embedding gather: A[m][i] = emb_w[tok[m]][i] ----------------
__global__ __launch_bounds__(256) void embed_kernel(const int* __restrict__ tok,
                                                    const float* __restrict__ emb_w,
                                                    float* __restrict__ A) {
    int idx = blockIdx.x * 256 + threadIdx.x;           // m*NINP + i
    if (idx >= MROWS * NINP) return;
    int m = idx / NINP, i = idx - m * NINP;
    int t = tok[m];
    A[idx] = emb_w[(size_t)t * NINP + i];
}

// ---------------- fp32 copy ----------------
__global__ __launch_bounds__(256) void copy_kernel(const float* __restrict__ src,
                                                   float* __restrict__ dst, int n) {
    int idx = blockIdx.x * 256 + threadIdx.x;
    if (idx < n) dst[idx] = src[idx];
}

// ---------------- C[m][n] = sum_k A[m][k]*W[n][k] + bias[n] ----------------
// A fp32 MxK, W fp32 NxK (row-major = B^T layout), bias fp32 N
__global__ __launch_bounds__(256) void gemm_bt(const float* __restrict__ A,
                                               const float* __restrict__ W,
                                               const float* __restrict__ bias,
                                               float* __restrict__ C,
                                               int M, int N, int K) {
    __shared__ float As[32][33];
    __shared__ float Ws[32][33];
    int tx = threadIdx.x & 15, ty = threadIdx.x >> 4;   // 16x16 threads, 2x2 per thread
    int row0 = blockIdx.x * 32, col0 = blockIdx.y * 32;
    float acc00 = 0.f, acc01 = 0.f, acc10 = 0.f, acc11 = 0.f;
    for (int k0 = 0; k0 < K; k0 += 32) {
        for (int r = 0; r < 4; ++r) {
            int idx = threadIdx.x + r * 256;
            int ar = idx >> 5, ak = idx & 31;
            int m = row0 + ar, k = k0 + ak;
            As[ar][ak] = (m < M && k < K) ? A[(size_t)m * K + k] : 0.f;
            int n = col0 + ar;
            Ws[ar][ak] = (n < N && k < K) ? W[(size_t)n * K + k] : 0.f;
        }
        __syncthreads();
#pragma unroll
        for (int kk = 0; kk < 32; ++kk) {
            float a0 = As[ty][kk], a1 = As[ty + 16][kk];
            float w0 = Ws[tx][kk], w1 = Ws[tx + 16][kk];
            acc00 += a0 * w0; acc01 += a0 * w1;
            acc10 += a1 * w0; acc11 += a1 * w1;
        }
        __syncthreads();
    }
    int m0 = row0 + ty, m1 = row0 + ty + 16;
    int n0 = col0 + tx, n1 = col0 + tx + 16;
    if (m0 < M && n0 < N) C[(size_t)m0 * N + n0] = acc00 + bias[n0];
    if (m0 < M && n1 < N) C[(size_t)m0 * N + n1] = acc01 + bias[n1];
    if (m1 < M && n0 < N) C[(size_t)m1 * N + n0] = acc10 + bias[n0];
    if (m1 < M && n1 < N) C[(size_t)m1 * N + n1] = acc11 + bias[n1];
}

// ---------------- one LSTM timestep, fused: pre = xpre + h@wh^T + bh; gates; c,h ----------------
// gate layout in rows of wh/bh and cols of xpre: [f | i | o | g], each n wide.
// block: 256 threads = 64 batch x 4 gate-columns. grid.x = ceil(n/4).
__global__ __launch_bounds__(256) void lstm_step(const float* __restrict__ xpre,  // B x 4n
                                                 const float* __restrict__ hprev, // B x n
                                                 float* __restrict__ c,           // B x n (in place)
                                                 const float* __restrict__ wh,    // 4n x n
                                                 const float* __restrict__ bh,    // 4n
                                                 float* __restrict__ hout,        // B x n
                                                 int n) {
    __shared__ float Hs[64][33];
    __shared__ float Ws[16][33];
    int tid = threadIdx.x;
    int b = tid & 63, jj = tid >> 6;
    int j = blockIdx.x * 4 + jj;
    float accf = 0.f, acci = 0.f, acco = 0.f, accg = 0.f;
    for (int k0 = 0; k0 < n; k0 += 32) {
        // stage 64x32 tile of hprev
        for (int r = 0; r < 8; ++r) {
            int idx = tid + r * 256;
            int hb = idx >> 5, kk = idx & 31;
            int k = k0 + kk;
            Hs[hb][kk] = (k < n) ? hprev[hb * n + k] : 0.f;
        }
        // stage 16 rows of wh (4 gates x 4 j's), 32 k each
        for (int r = 0; r < 2; ++r) {
            int idx = tid + r * 256;
            int wr = idx >> 5, kk = idx & 31;
            int gi = wr >> 2, jr = wr & 3;
            int jb = blockIdx.x * 4 + jr;
            int k = k0 + kk;
            Ws[wr][kk] = (jb < n && k < n) ? wh[(size_t)(gi * n + jb) * n + k] : 0.f;
        }
        __syncthreads();
#pragma unroll
        for (int kk = 0; kk < 32; ++kk) {
            float hv = Hs[b][kk];
            accf += hv * Ws[jj][kk];
            acci += hv * Ws[4 + jj][kk];
            acco += hv * Ws[8 + jj][kk];
            accg += hv * Ws[12 + jj][kk];
        }
        __syncthreads();
    }
    if (j < n) {
        int g4 = 4 * n;
        float pf = accf + xpre[b * g4 + j]         + bh[j];
        float pi = acci + xpre[b * g4 + n + j]     + bh[n + j];
        float po = acco + xpre[b * g4 + 2 * n + j] + bh[2 * n + j];
        float pg = accg + xpre[b * g4 + 3 * n + j] + bh[3 * n + j];
        float f = 1.f / (1.f + expf(-pf));
        float i = 1.f / (1.f + expf(-pi));
        float o = 1.f / (1.f + expf(-po));
        float g = tanhf(pg);
        float cn = f * c[b * n + j] + i * g;
        c[b * n + j] = cn;
        hout[b * n + j] = o * tanhf(cn);
    }
}

extern "C" void kernel_launch(void* const* d_in, const int* in_sizes, int n_in,
                              void* d_out, int out_size, void* d_ws, size_t ws_size,
                              hipStream_t stream) {
    const int*   tok   = (const int*)d_in[0];
    const float* h0    = (const float*)d_in[1];
    const float* c0    = (const float*)d_in[2];
    const float* h1    = (const float*)d_in[3];
    const float* c1    = (const float*)d_in[4];
    const float* h2    = (const float*)d_in[5];
    const float* c2    = (const float*)d_in[6];
    const float* emb_w = (const float*)d_in[7];
    const float* wi[3] = {(const float*)d_in[8],  (const float*)d_in[12], (const float*)d_in[16]};
    const float* bi[3] = {(const float*)d_in[9],  (const float*)d_in[13], (const float*)d_in[17]};
    const float* wh[3] = {(const float*)d_in[10], (const float*)d_in[14], (const float*)d_in[18]};
    const float* bh[3] = {(const float*)d_in[11], (const float*)d_in[15], (const float*)d_in[19]};
    const float* dec_b = (const float*)d_in[20];
    const float* hinit[3] = {h0, h1, h2};
    const float* cinit[3] = {c0, c1, c2};
    const int din[3]  = {NINP, NHID, NHID};
    const int dout[3] = {NHID, NHID, NINP};

    // ws layout (floats):
    //   bufA [0, 5152000)          activation ping  (4480*1150 max)
    //   bufB [5152000, 10304000)   activation pong
    //   P    [10304000, 30912000)  x_pre (4480*4600 max)
    //   cb   [30912000, +73600)    fp32 c state (updated in place; inputs never mutated)
    float* ws   = (float*)d_ws;
    float* bufA = ws;
    float* bufB = ws + 5152000;
    float* P    = ws + 10304000;
    float* cb   = ws + 30912000;

    // 1) embedding -> bufA
    embed_kernel<<<(MROWS * NINP + 255) / 256, 256, 0, stream>>>(tok, emb_w, bufA);

    float* xs = bufA;   // current layer input (M x din)
    float* hs = bufB;   // current layer output (M x dout)
    for (int l = 0; l < 3; ++l) {
        int G = 4 * dout[l];
        // 2) x_pre = xs @ wi^T + bi   (M x G)
        dim3 g1(MROWS / 32, (G + 31) / 32);
        gemm_bt<<<g1, 256, 0, stream>>>(xs, wi[l], bi[l], P, MROWS, G, din[l]);
        // 3) init c state (copy; h init read directly from input)
        int bn = BATCH * dout[l];
        copy_kernel<<<(bn + 255) / 256, 256, 0, stream>>>(cinit[l], cb, bn);
        // 4) scan
        for (int t = 0; t < T_STEPS; ++t) {
            const float* hp = (t == 0) ? hinit[l] : hs + (size_t)(t - 1) * BATCH * dout[l];
            lstm_step<<<(dout[l] + 3) / 4, 256, 0, stream>>>(
                P + (size_t)t * BATCH * G, hp, cb, wh[l], bh[l],
                hs + (size_t)t * BATCH * dout[l], dout[l]);
        }
        float* tmp = xs; xs = hs; hs = tmp;   // this layer's hs is next layer's input
    }

    // 5) decoder: out = xs @ emb_w^T + dec_b  (4480 x 33278), fp32 out
    dim3 g2(MROWS / 32, (NTOKEN + 31) / 32);
    gemm_bt<<<g2, 256, 0, stream>>>(xs, emb_w, dec_b, (float*)d_out, MROWS, NTOKEN, NINP);
}